// Round 1
// baseline (25761.469 us; speedup 1.0000x reference)
//
#include <hip/hip_runtime.h>

// Seq2Seq LSTM (E=256,H=512,B=1024,S=128,T=128). FP32 in/out.
// Round 8: single persistent kernel for all 255 recurrent steps + fused FC.
//  - grid (32,16)=512 blocks, 2/CU (structurally guaranteed via launch_bounds).
//  - per-by-group (32 block) generation barrier with device-scope atomics.
//  - c kept in registers across all steps (block-private tile).
//  - FC fused as post-barrier phase of decoder steps.
// GEMM inner loop / hi-lo split numerics identical to verified round-7 kernel.

typedef unsigned short u16;
typedef __attribute__((ext_vector_type(8))) short short8;
typedef __attribute__((ext_vector_type(4))) float floatx4;

__device__ __forceinline__ float bf2f(u16 s) {
  union { unsigned int u; float f; } v; v.u = ((unsigned int)s) << 16; return v.f;
}
__device__ __forceinline__ u16 f2bf(float x) {
  union { float f; unsigned int u; } v; v.f = x;
  unsigned int r = (v.u + 0x7FFFu + ((v.u >> 16) & 1u)) >> 16;
  return (u16)r;
}
__device__ __forceinline__ void split2(float x, u16* hi, u16* lo) {
  u16 h = f2bf(x);
  *hi = h;
  *lo = f2bf(x - bf2f(h));
}
__device__ __forceinline__ float sigm(float x) { return 1.0f / (1.0f + expf(-x)); }

// ---------------------------------------------------------------- prep ------
__global__ __launch_bounds__(256) void prep_m(
    const float* __restrict__ e_wih, const float* __restrict__ e_whh,
    const float* __restrict__ e_bih, const float* __restrict__ e_bhh,
    const float* __restrict__ d_wih, const float* __restrict__ d_whh,
    const float* __restrict__ d_bih, const float* __restrict__ d_bhh,
    const float* __restrict__ emb, const float* __restrict__ dec_emb,
    u16* __restrict__ WhiE, u16* __restrict__ WloE,
    u16* __restrict__ WhiD, u16* __restrict__ WloD,
    float* __restrict__ bcE, float* __restrict__ bcD,
    u16* __restrict__ eHiE, u16* __restrict__ eLoE,
    u16* __restrict__ eHiD, u16* __restrict__ eLoD,
    u16* __restrict__ hHi, u16* __restrict__ hLo,
    float* __restrict__ out, unsigned* __restrict__ bar) {
  int idx0 = blockIdx.x * blockDim.x + threadIdx.x;
  int stride = gridDim.x * blockDim.x;
  for (int i = idx0; i < 2048 * 768; i += stride) {
    int rr = i / 768, k = i - rr * 768;
    int j = rr >> 2, g = rr & 3;
    int orig = g * 512 + j;  // reference gate order i,f,g,o
    float we = (k < 256) ? e_wih[orig * 256 + k] : e_whh[orig * 512 + (k - 256)];
    float wd = (k < 256) ? d_wih[orig * 256 + k] : d_whh[orig * 512 + (k - 256)];
    split2(we, &WhiE[i], &WloE[i]);
    split2(wd, &WhiD[i], &WloD[i]);
  }
  for (int i = idx0; i < 2048; i += stride) {
    int j = i >> 2, g = i & 3, orig = g * 512 + j;
    bcE[i] = e_bih[orig] + e_bhh[orig];
    bcD[i] = d_bih[orig] + d_bhh[orig];
  }
  for (int i = idx0; i < 128 * 256; i += stride) {
    split2(emb[i], &eHiE[i], &eLoE[i]);
    split2(dec_emb[i], &eHiD[i], &eLoD[i]);
  }
  for (int i = idx0; i < 1024 * 512; i += stride) {
    hHi[i] = 0; hLo[i] = 0;
  }
  for (int i = idx0; i < 1024 * 128; i += stride)
    out[(i >> 7) * 16384 + (i & 127)] = 0.0f;  // out[:,0,:] = 0
  for (int i = idx0; i < 512; i += stride) bar[i] = 0u;
}

// ------------------------------------------------------- persistent body ----
// grid (32,16): bx -> n0 (interleaved gate cols), by -> m0 (batch). 256 thr.
// 64x64 tile, 4 waves, 2x2 MFMA 16x16x32, 3-term hi/lo split. Loops phases
// (encoder 128 steps, decoder 127 steps) with a per-by-group barrier per step.
__global__ __launch_bounds__(256, 2) void seq2seq_persist(
    const u16* __restrict__ eHiE, const u16* __restrict__ eLoE,
    const u16* __restrict__ eHiD, const u16* __restrict__ eLoD,
    const int* __restrict__ src, const int* __restrict__ tgt,
    const u16* __restrict__ WhiE, const u16* __restrict__ WloE,
    const u16* __restrict__ WhiD, const u16* __restrict__ WloD,
    const float* __restrict__ bcE, const float* __restrict__ bcD,
    u16* __restrict__ hHiA, u16* __restrict__ hLoA,
    u16* __restrict__ hHiB, u16* __restrict__ hLoB,
    const float* __restrict__ fc_w, const float* __restrict__ fc_b,
    float* __restrict__ out, unsigned* __restrict__ bar) {
  __shared__ __align__(16) unsigned char smem[20480];  // 4 tiles, stride 40 sh
  __shared__ int sidx[64];
  short* sAhi = (short*)(smem);
  short* sAlo = (short*)(smem + 5120);
  short* sBhi = (short*)(smem + 10240);
  short* sBlo = (short*)(smem + 15360);
  const int tid = threadIdx.x;
  const int m0 = blockIdx.y * 64;
  const int n0 = blockIdx.x * 64;
  const int gby = blockIdx.y;

  // staging: thread stages row rs = tid>>2, 8 els at qo = (tid&3)*8
  const int rs = tid >> 2;
  const int qo = (tid & 3) * 8;
  const int so = rs * 40 + qo;  // LDS short offset
  const int aOffH = (m0 + rs) * 512 + qo;

  const int lane = tid & 63;
  const int wv = tid >> 6;
  const int wm = wv & 1, wn = wv >> 1;
  const int lr = lane & 15, lq = lane >> 4;
  const int ra0 = wm * 32 + lr, ra1 = ra0 + 16;
  const int rb0 = wn * 32 + lr, rb1 = rb0 + 16;
  const int oa0 = ra0 * 40 + lq * 8, oa1 = ra1 * 40 + lq * 8;
  const int ob0 = rb0 * 40 + lq * 8, ob1 = rb1 * 40 + lq * 8;

  float creg[4] = {0.f, 0.f, 0.f, 0.f};  // cell state, block-private tile
  unsigned gen = 0;

  u16* hIa = hHiA; u16* lIa = hLoA;   // "in" buffers
  u16* hIb = hHiB; u16* lIb = hLoB;   // "out" buffers

  for (int phase = 0; phase < 2; ++phase) {
    const u16* eHi = phase ? eHiD : eHiE;
    const u16* eLo = phase ? eLoD : eLoE;
    const int* idx = phase ? tgt : src;
    const u16* Whi = phase ? WhiD : WhiE;
    const u16* Wlo = phase ? WloD : WloE;
    const float* bc = phase ? bcD : bcE;
    const int nsteps = phase ? 127 : 128;
    const u16* bHi = Whi + (n0 + rs) * 768 + qo;
    const u16* bLo = Wlo + (n0 + rs) * 768 + qo;

    for (int t = 0; t < nsteps; ++t) {
      if (tid < 64) sidx[tid] = idx[(m0 + tid) * 128 + t];
      __syncthreads();

      const u16* aHiE = eHi + sidx[rs] * 256 + qo;
      const u16* aLoE = eLo + sidx[rs] * 256 + qo;
      const u16* aHiH = hIa + aOffH;
      const u16* aLoH = lIa + aOffH;

      floatx4 acc00 = {0.f, 0.f, 0.f, 0.f}, acc01 = {0.f, 0.f, 0.f, 0.f};
      floatx4 acc10 = {0.f, 0.f, 0.f, 0.f}, acc11 = {0.f, 0.f, 0.f, 0.f};

      // 1-deep prefetch (kk=0 is emb region)
      short8 vah = *(const short8*)aHiE;
      short8 val = *(const short8*)aLoE;
      short8 vbh = *(const short8*)bHi;
      short8 vbl = *(const short8*)bLo;

      for (int kk = 0; kk < 24; ++kk) {
        *(short8*)&sAhi[so] = vah;
        *(short8*)&sAlo[so] = val;
        *(short8*)&sBhi[so] = vbh;
        *(short8*)&sBlo[so] = vbl;
        __syncthreads();
        if (kk < 23) {
          const int k1 = (kk + 1) * 32;
          if (k1 < 256) {
            vah = *(const short8*)(aHiE + k1);
            val = *(const short8*)(aLoE + k1);
          } else {
            vah = *(const short8*)(aHiH + (k1 - 256));
            val = *(const short8*)(aLoH + (k1 - 256));
          }
          vbh = *(const short8*)(bHi + k1);
          vbl = *(const short8*)(bLo + k1);
        }
        short8 ah0 = *(const short8*)&sAhi[oa0];
        short8 ah1 = *(const short8*)&sAhi[oa1];
        short8 al0 = *(const short8*)&sAlo[oa0];
        short8 al1 = *(const short8*)&sAlo[oa1];
        short8 bh0 = *(const short8*)&sBhi[ob0];
        short8 bh1 = *(const short8*)&sBhi[ob1];
        short8 bl0 = *(const short8*)&sBlo[ob0];
        short8 bl1 = *(const short8*)&sBlo[ob1];
        acc00 = __builtin_amdgcn_mfma_f32_16x16x32_bf16(al0, bh0, acc00, 0, 0, 0);
        acc00 = __builtin_amdgcn_mfma_f32_16x16x32_bf16(ah0, bl0, acc00, 0, 0, 0);
        acc00 = __builtin_amdgcn_mfma_f32_16x16x32_bf16(ah0, bh0, acc00, 0, 0, 0);
        acc01 = __builtin_amdgcn_mfma_f32_16x16x32_bf16(al0, bh1, acc01, 0, 0, 0);
        acc01 = __builtin_amdgcn_mfma_f32_16x16x32_bf16(ah0, bl1, acc01, 0, 0, 0);
        acc01 = __builtin_amdgcn_mfma_f32_16x16x32_bf16(ah0, bh1, acc01, 0, 0, 0);
        acc10 = __builtin_amdgcn_mfma_f32_16x16x32_bf16(al1, bh0, acc10, 0, 0, 0);
        acc10 = __builtin_amdgcn_mfma_f32_16x16x32_bf16(ah1, bl0, acc10, 0, 0, 0);
        acc10 = __builtin_amdgcn_mfma_f32_16x16x32_bf16(ah1, bh0, acc10, 0, 0, 0);
        acc11 = __builtin_amdgcn_mfma_f32_16x16x32_bf16(al1, bh1, acc11, 0, 0, 0);
        acc11 = __builtin_amdgcn_mfma_f32_16x16x32_bf16(ah1, bl1, acc11, 0, 0, 0);
        acc11 = __builtin_amdgcn_mfma_f32_16x16x32_bf16(ah1, bh1, acc11, 0, 0, 0);
        __syncthreads();
      }

      // gates -> LDS fp32 (stride 68 floats; reuses the tile memory)
      float* gl = (float*)smem;
      const int rowb = wm * 32 + lq * 4;
      const int colb = wn * 32 + lr;
#pragma unroll
      for (int j = 0; j < 4; ++j) {
        gl[(rowb + j) * 68 + colb] = acc00[j];
        gl[(rowb + j) * 68 + colb + 16] = acc01[j];
        gl[(rowb + 16 + j) * 68 + colb] = acc10[j];
        gl[(rowb + 16 + j) * 68 + colb + 16] = acc11[j];
      }
      __syncthreads();

      // fused LSTM cell: 64 rows x 16 units per block; c in registers
#pragma unroll
      for (int ii = 0; ii < 4; ++ii) {
        int pp = ii * 256 + tid;
        int row = pp >> 4;
        int u = pp & 15;
        const float* gp = gl + row * 68 + u * 4;
        float gi = gp[0], gf = gp[1], gg = gp[2], go = gp[3];
        const float* bp = bc + n0 + u * 4;
        gi += bp[0]; gf += bp[1]; gg += bp[2]; go += bp[3];
        int gb = m0 + row;
        int gu = (n0 >> 2) + u;
        int ci = gb * 512 + gu;
        float cold = creg[ii];
        float cn = sigm(gf) * cold + sigm(gi) * tanhf(gg);
        creg[ii] = cn;
        float h = sigm(go) * tanhf(cn);
        u16 hi, lo;
        split2(h, &hi, &lo);
        hIb[ci] = hi;
        lIb[ci] = lo;
      }

      // ---- per-by-group barrier (32 blocks), generation-counted ----
      gen += 32;
      __threadfence();   // release own h stores to device scope
      __syncthreads();
      if (tid == 0) {
        atomicAdd(&bar[gby * 32], 1u);
        while (__hip_atomic_load(&bar[gby * 32], __ATOMIC_RELAXED,
                                 __HIP_MEMORY_SCOPE_AGENT) < gen)
          __builtin_amdgcn_s_sleep(4);
        __threadfence();  // acquire: invalidate caches before reading peer h
      }
      __syncthreads();

      // ---- fused FC (decoder only): out[:, t+1, :] = h @ fc_w^T + fc_b ----
      if (phase == 1) {
        const int r = m0 + ((blockIdx.x >> 3) << 4) + (tid >> 4);
        const int v = ((blockIdx.x & 7) << 4) + (tid & 15);
        const u16* ph = hIb + r * 512;
        const u16* pl = lIb + r * 512;
        const float* pw = fc_w + v * 512;
        float acc = 0.f;
        for (int k = 0; k < 512; k += 8) {
          short8 vh = *(const short8*)(ph + k);
          short8 vl = *(const short8*)(pl + k);
          floatx4 w0 = *(const floatx4*)(pw + k);
          floatx4 w1 = *(const floatx4*)(pw + k + 4);
#pragma unroll
          for (int j = 0; j < 4; ++j) {
            acc += (bf2f((u16)vh[j]) + bf2f((u16)vl[j])) * w0[j];
            acc += (bf2f((u16)vh[4 + j]) + bf2f((u16)vl[4 + j])) * w1[j];
          }
        }
        out[r * 16384 + (t + 1) * 128 + v] = acc + fc_b[v];
      }

      // swap h ping-pong
      u16* th = hIa; hIa = hIb; hIb = th;
      u16* tl = lIa; lIa = lIb; lIb = tl;
    }
  }
}

// ---------------------------------------------------------------- launch ----
extern "C" void kernel_launch(void* const* d_in, const int* in_sizes, int n_in,
                              void* d_out, int out_size, void* d_ws, size_t ws_size,
                              hipStream_t stream) {
  const int* src = (const int*)d_in[0];
  const int* tgt = (const int*)d_in[1];
  const float* emb = (const float*)d_in[2];
  const float* dec_emb = (const float*)d_in[3];
  const float* e_wih = (const float*)d_in[4];
  const float* e_whh = (const float*)d_in[5];
  const float* e_bih = (const float*)d_in[6];
  const float* e_bhh = (const float*)d_in[7];
  const float* d_wih = (const float*)d_in[8];
  const float* d_whh = (const float*)d_in[9];
  const float* d_bih = (const float*)d_in[10];
  const float* d_bhh = (const float*)d_in[11];
  const float* fc_w = (const float*)d_in[12];
  const float* fc_b = (const float*)d_in[13];
  float* out = (float*)d_out;

  char* ws = (char*)d_ws;
  u16* WhiE = (u16*)(ws + 0);             // 3,145,728
  u16* WloE = (u16*)(ws + 3145728);       // 3,145,728
  u16* WhiD = (u16*)(ws + 6291456);       // 3,145,728
  u16* WloD = (u16*)(ws + 9437184);       // 3,145,728
  float* bcE = (float*)(ws + 12582912);   // 8,192
  float* bcD = (float*)(ws + 12591104);   // 8,192
  u16* eHiE = (u16*)(ws + 12599296);      // 65,536
  u16* eLoE = (u16*)(ws + 12664832);      // 65,536
  u16* eHiD = (u16*)(ws + 12730368);      // 65,536
  u16* eLoD = (u16*)(ws + 12795904);      // 65,536
  u16* hHiA = (u16*)(ws + 12861440);      // 1,048,576
  u16* hLoA = (u16*)(ws + 13910016);      // 1,048,576
  u16* hHiB = (u16*)(ws + 14958592);      // 1,048,576
  u16* hLoB = (u16*)(ws + 16007168);      // 1,048,576
  unsigned* bar = (unsigned*)(ws + 17055744);  // 2,048   (total ~17.1 MB)

  prep_m<<<1024, 256, 0, stream>>>(e_wih, e_whh, e_bih, e_bhh,
                                   d_wih, d_whh, d_bih, d_bhh,
                                   emb, dec_emb,
                                   WhiE, WloE, WhiD, WloD, bcE, bcD,
                                   eHiE, eLoE, eHiD, eLoD,
                                   hHiA, hLoA, out, bar);

  void* ka[] = {
      (void*)&eHiE, (void*)&eLoE, (void*)&eHiD, (void*)&eLoD,
      (void*)&src, (void*)&tgt,
      (void*)&WhiE, (void*)&WloE, (void*)&WhiD, (void*)&WloD,
      (void*)&bcE, (void*)&bcD,
      (void*)&hHiA, (void*)&hLoA, (void*)&hHiB, (void*)&hLoB,
      (void*)&fc_w, (void*)&fc_b, (void*)&out, (void*)&bar};
  hipError_t ce = hipLaunchCooperativeKernel(
      (const void*)seq2seq_persist, dim3(32, 16), dim3(256), ka, 0, stream);
  if (ce != hipSuccess) {
    // co-residency is structurally guaranteed (launch_bounds(256,2), 512
    // blocks = 2/CU) — plain launch is safe if cooperative path unavailable.
    (void)hipGetLastError();
    seq2seq_persist<<<dim3(32, 16), 256, 0, stream>>>(
        eHiE, eLoE, eHiD, eLoD, src, tgt, WhiE, WloE, WhiD, WloD,
        bcE, bcD, hHiA, hLoA, hHiB, hLoB, fc_w, fc_b, out, bar);
  }
}

// Round 2
// 14755.809 us; speedup vs baseline: 1.7459x; 1.7459x over previous
//
#include <hip/hip_runtime.h>

// Seq2Seq LSTM (E=256,H=512,B=1024,S=128,T=128). FP32 in/out.
// Round 9: persistent kernel, per-address coherence (no cache-wide fences).
//  - h exchanged via relaxed AGENT-scope atomic u32 stores/loads (write-through
//    to L3 / bypass stale L1+L2). Weights stay L2-resident across all steps.
//  - per-group barrier: 32 flag slots, atomic store + 32-lane parallel poll.
//  - depth-2 staging prefetch to hide L3 latency of bypass h loads.
//  - c in registers; FC fused into decoder steps.
// GEMM inner loop / hi-lo split numerics identical to verified round-7 kernel.

typedef unsigned short u16;
typedef __attribute__((ext_vector_type(8))) short short8;
typedef __attribute__((ext_vector_type(4))) float floatx4;

__device__ __forceinline__ float bf2f(u16 s) {
  union { unsigned int u; float f; } v; v.u = ((unsigned int)s) << 16; return v.f;
}
__device__ __forceinline__ u16 f2bf(float x) {
  union { float f; unsigned int u; } v; v.f = x;
  unsigned int r = (v.u + 0x7FFFu + ((v.u >> 16) & 1u)) >> 16;
  return (u16)r;
}
__device__ __forceinline__ void split2(float x, u16* hi, u16* lo) {
  u16 h = f2bf(x);
  *hi = h;
  *lo = f2bf(x - bf2f(h));
}
__device__ __forceinline__ float sigm(float x) { return 1.0f / (1.0f + expf(-x)); }

// ---------------------------------------------------------------- prep ------
__global__ __launch_bounds__(256) void prep_m(
    const float* __restrict__ e_wih, const float* __restrict__ e_whh,
    const float* __restrict__ e_bih, const float* __restrict__ e_bhh,
    const float* __restrict__ d_wih, const float* __restrict__ d_whh,
    const float* __restrict__ d_bih, const float* __restrict__ d_bhh,
    const float* __restrict__ emb, const float* __restrict__ dec_emb,
    u16* __restrict__ WhiE, u16* __restrict__ WloE,
    u16* __restrict__ WhiD, u16* __restrict__ WloD,
    float* __restrict__ bcE, float* __restrict__ bcD,
    u16* __restrict__ eHiE, u16* __restrict__ eLoE,
    u16* __restrict__ eHiD, u16* __restrict__ eLoD,
    u16* __restrict__ hHi, u16* __restrict__ hLo,
    float* __restrict__ out, unsigned* __restrict__ bar) {
  int idx0 = blockIdx.x * blockDim.x + threadIdx.x;
  int stride = gridDim.x * blockDim.x;
  for (int i = idx0; i < 2048 * 768; i += stride) {
    int rr = i / 768, k = i - rr * 768;
    int j = rr >> 2, g = rr & 3;
    int orig = g * 512 + j;  // reference gate order i,f,g,o
    float we = (k < 256) ? e_wih[orig * 256 + k] : e_whh[orig * 512 + (k - 256)];
    float wd = (k < 256) ? d_wih[orig * 256 + k] : d_whh[orig * 512 + (k - 256)];
    split2(we, &WhiE[i], &WloE[i]);
    split2(wd, &WhiD[i], &WloD[i]);
  }
  for (int i = idx0; i < 2048; i += stride) {
    int j = i >> 2, g = i & 3, orig = g * 512 + j;
    bcE[i] = e_bih[orig] + e_bhh[orig];
    bcD[i] = d_bih[orig] + d_bhh[orig];
  }
  for (int i = idx0; i < 128 * 256; i += stride) {
    split2(emb[i], &eHiE[i], &eLoE[i]);
    split2(dec_emb[i], &eHiD[i], &eLoD[i]);
  }
  for (int i = idx0; i < 1024 * 512; i += stride) {
    hHi[i] = 0; hLo[i] = 0;
  }
  for (int i = idx0; i < 1024 * 128; i += stride)
    out[(i >> 7) * 16384 + (i & 127)] = 0.0f;  // out[:,0,:] = 0
  for (int i = idx0; i < 512; i += stride) bar[i] = 0u;
}

// one pipelined K-slab: LDS write (slot), prefetch kk+2 into slot, frag+MFMA
#define GSTEP(VAH, VAL, VBH, VBL, KK)                                          \
  {                                                                            \
    *(short8*)&sAhi[so] = VAH;                                                 \
    *(short8*)&sAlo[so] = VAL;                                                 \
    *(short8*)&sBhi[so] = VBH;                                                 \
    *(short8*)&sBlo[so] = VBL;                                                 \
    __syncthreads();                                                           \
    if ((KK) < 22) {                                                           \
      const int k1_ = ((KK) + 2) * 32;                                         \
      if (k1_ < 256) {                                                         \
        VAH = *(const short8*)(aHiE + k1_);                                    \
        VAL = *(const short8*)(aLoE + k1_);                                    \
      } else {                                                                 \
        const unsigned* ph_ = (const unsigned*)(aHiH + (k1_ - 256));           \
        const unsigned* pl_ = (const unsigned*)(aLoH + (k1_ - 256));           \
        union { unsigned u[4]; short8 s; } uh_, ul_;                           \
        _Pragma("unroll")                                                      \
        for (int j_ = 0; j_ < 4; ++j_) {                                       \
          uh_.u[j_] = __hip_atomic_load(ph_ + j_, __ATOMIC_RELAXED,            \
                                        __HIP_MEMORY_SCOPE_AGENT);             \
          ul_.u[j_] = __hip_atomic_load(pl_ + j_, __ATOMIC_RELAXED,            \
                                        __HIP_MEMORY_SCOPE_AGENT);             \
        }                                                                      \
        VAH = uh_.s;                                                           \
        VAL = ul_.s;                                                           \
      }                                                                        \
      VBH = *(const short8*)(bHi + k1_);                                       \
      VBL = *(const short8*)(bLo + k1_);                                       \
    }                                                                          \
    {                                                                          \
      short8 ah0 = *(const short8*)&sAhi[oa0];                                 \
      short8 ah1 = *(const short8*)&sAhi[oa1];                                 \
      short8 al0 = *(const short8*)&sAlo[oa0];                                 \
      short8 al1 = *(const short8*)&sAlo[oa1];                                 \
      short8 bh0 = *(const short8*)&sBhi[ob0];                                 \
      short8 bh1 = *(const short8*)&sBhi[ob1];                                 \
      short8 bl0 = *(const short8*)&sBlo[ob0];                                 \
      short8 bl1 = *(const short8*)&sBlo[ob1];                                 \
      acc00 = __builtin_amdgcn_mfma_f32_16x16x32_bf16(al0, bh0, acc00, 0, 0, 0); \
      acc00 = __builtin_amdgcn_mfma_f32_16x16x32_bf16(ah0, bl0, acc00, 0, 0, 0); \
      acc00 = __builtin_amdgcn_mfma_f32_16x16x32_bf16(ah0, bh0, acc00, 0, 0, 0); \
      acc01 = __builtin_amdgcn_mfma_f32_16x16x32_bf16(al0, bh1, acc01, 0, 0, 0); \
      acc01 = __builtin_amdgcn_mfma_f32_16x16x32_bf16(ah0, bl1, acc01, 0, 0, 0); \
      acc01 = __builtin_amdgcn_mfma_f32_16x16x32_bf16(ah0, bh1, acc01, 0, 0, 0); \
      acc10 = __builtin_amdgcn_mfma_f32_16x16x32_bf16(al1, bh0, acc10, 0, 0, 0); \
      acc10 = __builtin_amdgcn_mfma_f32_16x16x32_bf16(ah1, bl0, acc10, 0, 0, 0); \
      acc10 = __builtin_amdgcn_mfma_f32_16x16x32_bf16(ah1, bh0, acc10, 0, 0, 0); \
      acc11 = __builtin_amdgcn_mfma_f32_16x16x32_bf16(al1, bh1, acc11, 0, 0, 0); \
      acc11 = __builtin_amdgcn_mfma_f32_16x16x32_bf16(ah1, bl1, acc11, 0, 0, 0); \
      acc11 = __builtin_amdgcn_mfma_f32_16x16x32_bf16(ah1, bh1, acc11, 0, 0, 0); \
    }                                                                          \
    __syncthreads();                                                           \
  }

// ------------------------------------------------------- persistent body ----
__global__ __launch_bounds__(256, 2) void seq2seq_persist(
    const u16* __restrict__ eHiE, const u16* __restrict__ eLoE,
    const u16* __restrict__ eHiD, const u16* __restrict__ eLoD,
    const int* __restrict__ src, const int* __restrict__ tgt,
    const u16* __restrict__ WhiE, const u16* __restrict__ WloE,
    const u16* __restrict__ WhiD, const u16* __restrict__ WloD,
    const float* __restrict__ bcE, const float* __restrict__ bcD,
    u16* __restrict__ hHiA, u16* __restrict__ hLoA,
    u16* __restrict__ hHiB, u16* __restrict__ hLoB,
    const float* __restrict__ fc_w, const float* __restrict__ fc_b,
    float* __restrict__ out, unsigned* __restrict__ bar) {
  __shared__ __align__(16) unsigned char smem[20480];  // 4 tiles, stride 40 sh
  __shared__ int sidx[64];
  short* sAhi = (short*)(smem);
  short* sAlo = (short*)(smem + 5120);
  short* sBhi = (short*)(smem + 10240);
  short* sBlo = (short*)(smem + 15360);
  const int tid = threadIdx.x;
  const int m0 = blockIdx.y * 64;
  const int n0 = blockIdx.x * 64;
  const int gby = blockIdx.y;

  // staging: thread stages row rs = tid>>2, 8 els at qo = (tid&3)*8
  const int rs = tid >> 2;
  const int qo = (tid & 3) * 8;
  const int so = rs * 40 + qo;  // LDS short offset
  const int aOffH = (m0 + rs) * 512 + qo;

  const int lane = tid & 63;
  const int wv = tid >> 6;
  const int wm = wv & 1, wn = wv >> 1;
  const int lr = lane & 15, lq = lane >> 4;
  const int ra0 = wm * 32 + lr, ra1 = ra0 + 16;
  const int rb0 = wn * 32 + lr, rb1 = rb0 + 16;
  const int oa0 = ra0 * 40 + lq * 8, oa1 = ra1 * 40 + lq * 8;
  const int ob0 = rb0 * 40 + lq * 8, ob1 = rb1 * 40 + lq * 8;

  float creg[4] = {0.f, 0.f, 0.f, 0.f};  // cell state, block-private tile
  unsigned gen = 0;

  u16* hIa = hHiA; u16* lIa = hLoA;   // "in" buffers
  u16* hIb = hHiB; u16* lIb = hLoB;   // "out" buffers

  for (int phase = 0; phase < 2; ++phase) {
    const u16* eHi = phase ? eHiD : eHiE;
    const u16* eLo = phase ? eLoD : eLoE;
    const int* idx = phase ? tgt : src;
    const float* bc = phase ? bcD : bcE;
    const int nsteps = phase ? 127 : 128;
    const u16* bHi = (phase ? WhiD : WhiE) + (n0 + rs) * 768 + qo;
    const u16* bLo = (phase ? WloD : WloE) + (n0 + rs) * 768 + qo;

    for (int t = 0; t < nsteps; ++t) {
      if (tid < 64) sidx[tid] = idx[(m0 + tid) * 128 + t];
      __syncthreads();

      const u16* aHiE = eHi + sidx[rs] * 256 + qo;
      const u16* aLoE = eLo + sidx[rs] * 256 + qo;
      const u16* aHiH = hIa + aOffH;
      const u16* aLoH = lIa + aOffH;

      floatx4 acc00 = {0.f, 0.f, 0.f, 0.f}, acc01 = {0.f, 0.f, 0.f, 0.f};
      floatx4 acc10 = {0.f, 0.f, 0.f, 0.f}, acc11 = {0.f, 0.f, 0.f, 0.f};

      // depth-2 prefetch preload (kk=0,1 are emb region)
      short8 vah0 = *(const short8*)aHiE;
      short8 val0 = *(const short8*)aLoE;
      short8 vbh0 = *(const short8*)bHi;
      short8 vbl0 = *(const short8*)bLo;
      short8 vah1 = *(const short8*)(aHiE + 32);
      short8 val1 = *(const short8*)(aLoE + 32);
      short8 vbh1 = *(const short8*)(bHi + 32);
      short8 vbl1 = *(const short8*)(bLo + 32);

#pragma unroll
      for (int kk = 0; kk < 24; kk += 2) {
        GSTEP(vah0, val0, vbh0, vbl0, kk)
        GSTEP(vah1, val1, vbh1, vbl1, kk + 1)
      }

      // gates -> LDS fp32 (stride 68 floats; reuses the tile memory)
      float* gl = (float*)smem;
      const int rowb = wm * 32 + lq * 4;
      const int colb = wn * 32 + lr;
#pragma unroll
      for (int j = 0; j < 4; ++j) {
        gl[(rowb + j) * 68 + colb] = acc00[j];
        gl[(rowb + j) * 68 + colb + 16] = acc01[j];
        gl[(rowb + 16 + j) * 68 + colb] = acc10[j];
        gl[(rowb + 16 + j) * 68 + colb + 16] = acc11[j];
      }
      __syncthreads();

      // fused LSTM cell: 64 rows x 16 units; c in regs; h out via agent-
      // scope write-through u32 stores (paired hi/lo u16)
#pragma unroll
      for (int ii = 0; ii < 2; ++ii) {
        int pp = ii * 256 + tid;      // 0..511
        int row = pp >> 3;            // 0..63
        int up = (pp & 7) * 2;        // 0,2,...,14
        const float* gp = gl + row * 68 + up * 4;
        const float* bp = bc + n0 + up * 4;
        float h0, h1;
        {
          float gi = gp[0] + bp[0], gf = gp[1] + bp[1];
          float gg = gp[2] + bp[2], go = gp[3] + bp[3];
          float cn = sigm(gf) * creg[ii * 2] + sigm(gi) * tanhf(gg);
          creg[ii * 2] = cn;
          h0 = sigm(go) * tanhf(cn);
        }
        {
          float gi = gp[4] + bp[4], gf = gp[5] + bp[5];
          float gg = gp[6] + bp[6], go = gp[7] + bp[7];
          float cn = sigm(gf) * creg[ii * 2 + 1] + sigm(gi) * tanhf(gg);
          creg[ii * 2 + 1] = cn;
          h1 = sigm(go) * tanhf(cn);
        }
        int ci = (m0 + row) * 512 + (n0 >> 2) + up;  // even
        u16 hi0, lo0, hi1, lo1;
        split2(h0, &hi0, &lo0);
        split2(h1, &hi1, &lo1);
        unsigned hp = (unsigned)hi0 | ((unsigned)hi1 << 16);
        unsigned lp = (unsigned)lo0 | ((unsigned)lo1 << 16);
        __hip_atomic_store((unsigned*)(hIb + ci), hp, __ATOMIC_RELAXED,
                           __HIP_MEMORY_SCOPE_AGENT);
        __hip_atomic_store((unsigned*)(lIb + ci), lp, __ATOMIC_RELAXED,
                           __HIP_MEMORY_SCOPE_AGENT);
      }

      // ---- per-group barrier: own flag slot + 32-lane parallel poll ----
      ++gen;
      __syncthreads();  // drains each thread's vmcnt before s_barrier
      if (tid == 0) {
        asm volatile("s_waitcnt vmcnt(0)" ::: "memory");
        __hip_atomic_store(&bar[(gby << 5) + blockIdx.x], gen,
                           __ATOMIC_RELAXED, __HIP_MEMORY_SCOPE_AGENT);
      }
      if (tid < 32) {
        while (__hip_atomic_load(&bar[(gby << 5) + tid], __ATOMIC_RELAXED,
                                 __HIP_MEMORY_SCOPE_AGENT) < gen)
          __builtin_amdgcn_s_sleep(2);
      }
      asm volatile("" ::: "memory");
      __syncthreads();

      // ---- fused FC (decoder only): out[:, t+1, :] = h @ fc_w^T + fc_b ----
      if (phase == 1) {
        const int r = m0 + ((blockIdx.x >> 3) << 4) + (tid >> 4);
        const int v = ((blockIdx.x & 7) << 4) + (tid & 15);
        const unsigned* ph = (const unsigned*)(hIb + r * 512);
        const unsigned* pl = (const unsigned*)(lIb + r * 512);
        const float* pw = fc_w + v * 512;
        float acc = 0.f;
        for (int k = 0; k < 256; k += 4) {  // u32 index over 512 u16
          union { unsigned u[4]; short8 s; } uh, ul;
#pragma unroll
          for (int j = 0; j < 4; ++j) {
            uh.u[j] = __hip_atomic_load(ph + k + j, __ATOMIC_RELAXED,
                                        __HIP_MEMORY_SCOPE_AGENT);
            ul.u[j] = __hip_atomic_load(pl + k + j, __ATOMIC_RELAXED,
                                        __HIP_MEMORY_SCOPE_AGENT);
          }
          floatx4 w0 = *(const floatx4*)(pw + 2 * k);
          floatx4 w1 = *(const floatx4*)(pw + 2 * k + 4);
#pragma unroll
          for (int j = 0; j < 4; ++j) {
            acc += (bf2f((u16)uh.s[j]) + bf2f((u16)ul.s[j])) * w0[j];
            acc += (bf2f((u16)uh.s[4 + j]) + bf2f((u16)ul.s[4 + j])) * w1[j];
          }
        }
        out[r * 16384 + (t + 1) * 128 + v] = acc + fc_b[v];
      }

      // swap h ping-pong
      u16* th = hIa; hIa = hIb; hIb = th;
      u16* tl = lIa; lIa = lIb; lIb = tl;
    }
  }
}

// ---------------------------------------------------------------- launch ----
extern "C" void kernel_launch(void* const* d_in, const int* in_sizes, int n_in,
                              void* d_out, int out_size, void* d_ws, size_t ws_size,
                              hipStream_t stream) {
  const int* src = (const int*)d_in[0];
  const int* tgt = (const int*)d_in[1];
  const float* emb = (const float*)d_in[2];
  const float* dec_emb = (const float*)d_in[3];
  const float* e_wih = (const float*)d_in[4];
  const float* e_whh = (const float*)d_in[5];
  const float* e_bih = (const float*)d_in[6];
  const float* e_bhh = (const float*)d_in[7];
  const float* d_wih = (const float*)d_in[8];
  const float* d_whh = (const float*)d_in[9];
  const float* d_bih = (const float*)d_in[10];
  const float* d_bhh = (const float*)d_in[11];
  const float* fc_w = (const float*)d_in[12];
  const float* fc_b = (const float*)d_in[13];
  float* out = (float*)d_out;

  char* ws = (char*)d_ws;
  u16* WhiE = (u16*)(ws + 0);             // 3,145,728
  u16* WloE = (u16*)(ws + 3145728);       // 3,145,728
  u16* WhiD = (u16*)(ws + 6291456);       // 3,145,728
  u16* WloD = (u16*)(ws + 9437184);       // 3,145,728
  float* bcE = (float*)(ws + 12582912);   // 8,192
  float* bcD = (float*)(ws + 12591104);   // 8,192
  u16* eHiE = (u16*)(ws + 12599296);      // 65,536
  u16* eLoE = (u16*)(ws + 12664832);      // 65,536
  u16* eHiD = (u16*)(ws + 12730368);      // 65,536
  u16* eLoD = (u16*)(ws + 12795904);      // 65,536
  u16* hHiA = (u16*)(ws + 12861440);      // 1,048,576
  u16* hLoA = (u16*)(ws + 13910016);      // 1,048,576
  u16* hHiB = (u16*)(ws + 14958592);      // 1,048,576
  u16* hLoB = (u16*)(ws + 16007168);      // 1,048,576
  unsigned* bar = (unsigned*)(ws + 17055744);  // 2,048   (total ~17.1 MB)

  prep_m<<<1024, 256, 0, stream>>>(e_wih, e_whh, e_bih, e_bhh,
                                   d_wih, d_whh, d_bih, d_bhh,
                                   emb, dec_emb,
                                   WhiE, WloE, WhiD, WloD, bcE, bcD,
                                   eHiE, eLoE, eHiD, eLoD,
                                   hHiA, hLoA, out, bar);

  void* ka[] = {
      (void*)&eHiE, (void*)&eLoE, (void*)&eHiD, (void*)&eLoD,
      (void*)&src, (void*)&tgt,
      (void*)&WhiE, (void*)&WloE, (void*)&WhiD, (void*)&WloD,
      (void*)&bcE, (void*)&bcD,
      (void*)&hHiA, (void*)&hLoA, (void*)&hHiB, (void*)&hLoB,
      (void*)&fc_w, (void*)&fc_b, (void*)&out, (void*)&bar};
  hipError_t ce = hipLaunchCooperativeKernel(
      (const void*)seq2seq_persist, dim3(32, 16), dim3(256), ka, 0, stream);
  if (ce != hipSuccess) {
    // co-residency is structurally guaranteed (launch_bounds(256,2), 512
    // blocks = 2/CU) — plain launch is safe if cooperative path unavailable.
    (void)hipGetLastError();
    seq2seq_persist<<<dim3(32, 16), 256, 0, stream>>>(
        eHiE, eLoE, eHiD, eLoD, src, tgt, WhiE, WloE, WhiD, WloD,
        bcE, bcD, hHiA, hLoA, hHiB, hLoB, fc_w, fc_b, out, bar);
  }
}